// Round 1
// baseline (12.938 us; speedup 1.0000x reference)
//
#include <hip/hip_runtime.h>

// Problem constants (match reference).
constexpr int B = 32, T = 4096, C = 32;
constexpr int NK = 3;     // W_ORDER = N_BREAKPOINTS - 1
constexpr int BVEC = 8;   // batches per thread (amortize scattered v/w loads)

// out[b,t,c] = v[c,0,t] + x*v[c,1,t] + sum_k basis_k(x) * w[c,k,t]
// basis_k(x) = inside ? 0.5*(x-klo)^2 : 0.5*dk*dk + dk*(x-khi)
// Thread decomposition: lane-fastest dim is c4 (4 contiguous channels ->
// float4 coalesced x/out), then t, then batch-group of 8.
__global__ __launch_bounds__(256) void saaf_kernel(
    const float* __restrict__ x,
    const float* __restrict__ v,
    const float* __restrict__ w,
    float* __restrict__ out)
{
    const int tid = blockIdx.x * blockDim.x + threadIdx.x;
    const int c4  = tid & 7;             // 8 groups of 4 channels
    const int t   = (tid >> 3) & (T - 1);
    const int bg  = tid >> 15;           // 0..3 (4 groups of BVEC=8 batches)
    const int c0  = c4 * 4;

    // Breakpoint constants, replicated in f32 exactly as the reference:
    // step = f32(4096/3); bp[k] = f32(k) * step  (note bp[3] == 4096.0f)
    const float step = (float)(4096.0 / 3.0);   // 1365.3333740234375f
    float klo[NK], khi[NK], dk[NK], hdk2[NK];
#pragma unroll
    for (int k = 0; k < NK; ++k) {
        klo[k]  = (float)k * step;
        khi[k]  = (float)(k + 1) * step;
        dk[k]   = khi[k] - klo[k];
        hdk2[k] = (0.5f * dk[k]) * dk[k];       // 0.5*dk*dk, reference order
    }

    // One-time scattered coefficient loads (stride 2*T / 3*T across c; these
    // live in L2/L3 and are reused 32x across batches).
    float v0[4], v1[4], w0[4], w1[4], w2[4];
#pragma unroll
    for (int i = 0; i < 4; ++i) {
        const int c = c0 + i;
        v0[i] = v[(c * 2 + 0) * T + t];
        v1[i] = v[(c * 2 + 1) * T + t];
        w0[i] = w[(c * 3 + 0) * T + t];
        w1[i] = w[(c * 3 + 1) * T + t];
        w2[i] = w[(c * 3 + 2) * T + t];
    }

#pragma unroll
    for (int bb = 0; bb < BVEC; ++bb) {
        const int b = bg * BVEC + bb;
        const size_t base = ((size_t)b * T + t) * C + c0;
        const float4 xv = *(const float4*)&x[base];
        const float xs[4] = {xv.x, xv.y, xv.z, xv.w};
        float os[4];
#pragma unroll
        for (int i = 0; i < 4; ++i) {
            const float xx = xs[i];
            float acc = v0[i] + xx * v1[i];          // sigma1
#pragma unroll
            for (int k = 0; k < NK; ++k) {
                const float d1 = xx - klo[k];
                const float f1 = 0.5f * (d1 * d1);
                const float f2 = hdk2[k] + dk[k] * (xx - khi[k]);
                const bool inside = (xx > klo[k]) && (xx < khi[k]);
                const float basis = inside ? f1 : f2;
                const float wk = (k == 0) ? w0[i] : (k == 1) ? w1[i] : w2[i];
                acc += basis * wk;                   // sigma2 accumulate
            }
            os[i] = acc;
        }
        float4 ov;
        ov.x = os[0]; ov.y = os[1]; ov.z = os[2]; ov.w = os[3];
        *(float4*)&out[base] = ov;
    }
}

extern "C" void kernel_launch(void* const* d_in, const int* in_sizes, int n_in,
                              void* d_out, int out_size, void* d_ws, size_t ws_size,
                              hipStream_t stream) {
    const float* x = (const float*)d_in[0];
    const float* v = (const float*)d_in[1];
    const float* w = (const float*)d_in[2];
    float* out = (float*)d_out;

    // Total threads: 8 (c4) * 4096 (t) * 4 (batch groups) = 131072
    const int threads = (T * (C / 4)) * (B / BVEC);
    const int block = 256;
    const int grid = threads / block;   // 512
    saaf_kernel<<<grid, block, 0, stream>>>(x, v, w, out);
}